// Round 9
// baseline (218.226 us; speedup 1.0000x reference)
//
#include <hip/hip_runtime.h>
#include <hip/hip_fp16.h>

#define NBINS 255
#define NPAIRS 32
#define BIGF 3.0e38f

// ws float-index layout:
//  [0     ,16384 ) E   [64][256] fp32, tail BIGF
//  [16384 ,32768 ) PE
//  [32768 ,36864 ) ME  [64][64] mids e[4m+3] (pad BIGF)
//  [36864 ,40960 ) MP
//  [40960 ,41984 ) CU  [64][16] coarse e[16j+15] (pad BIGF)
//  [41984 ,43008 ) CP
//  [43008 ,51200 ) W16 [64][256] fp16 PRE-SHIFTED
//  [51200 ,313344) P   [262144] fp32 partial logits
//  byte 1253376.. T16 [32][256][256] fp16 PRE-SHIFTED  (split: ws>=5447680)
//  byte 204800 .. T16 (mono fallback: ws>=4399104)

__device__ __forceinline__ void prep_edge_elem(int i,
        const float* __restrict__ edges, const float* __restrict__ pair_edges,
        const float* __restrict__ w, float* __restrict__ ws) {
    int f = i >> 8, j = i & 255;
    float* E  = ws;
    float* PE = ws + 16384;
    float* ME = ws + 32768;
    float* MP = ws + 36864;
    float* CU = ws + 40960;
    float* CP = ws + 41984;
    __half* W = (__half*)(ws + 43008);
    E[i]  = (j < NBINS) ? edges[f * NBINS + j]      : BIGF;
    PE[i] = (j < NBINS) ? pair_edges[f * NBINS + j] : BIGF;
    int src = (j < 255) ? j + 1 : 0;
    W[i]  = __float2half(w[f * 256 + src]);
    if (j < 64) {
        int idx = 4 * j + 3;
        ME[f * 64 + j] = (idx < NBINS) ? edges[f * NBINS + idx]      : BIGF;
        MP[f * 64 + j] = (idx < NBINS) ? pair_edges[f * NBINS + idx] : BIGF;
    }
    if (j < 16) {
        CU[f * 16 + j] = (j < 15) ? edges[f * NBINS + 16 * j + 15]      : BIGF;
        CP[f * 16 + j] = (j < 15) ? pair_edges[f * NBINS + 16 * j + 15] : BIGF;
    }
}

// split path: one prep dispatch does T16 + edges/mids/coarse/W16
__global__ void ebm_prep_all(const float* __restrict__ edges,
                             const float* __restrict__ pair_edges,
                             const float* __restrict__ w,
                             const float* __restrict__ tables,
                             float* __restrict__ ws,
                             unsigned short* __restrict__ T16o) {
    int i = blockIdx.x * blockDim.x + threadIdx.x;   // 2097152 threads
    int b = i & 255, a = (i >> 8) & 255, p = i >> 16;
    int ra = (a < 255) ? a + 1 : 0;
    int rb = (b < 255) ? b + 1 : 0;
    T16o[i] = __half_as_ushort(__float2half(tables[(p << 16) + (ra << 8) + rb]));
    if (i < 16384) prep_edge_elem(i, edges, pair_edges, w, ws);
}

// fallback preps
__global__ void ebm_prep(const float* __restrict__ edges,
                         const float* __restrict__ pair_edges,
                         const float* __restrict__ w,
                         float* __restrict__ ws) {
    int i = blockIdx.x * blockDim.x + threadIdx.x;   // 16384 threads
    prep_edge_elem(i, edges, pair_edges, w, ws);
}

__global__ void ebm_prep_tables(const float* __restrict__ tables,
                                unsigned short* __restrict__ o) {
    int i = blockIdx.x * blockDim.x + threadIdx.x;
    int b = i & 255, a = (i >> 8) & 255, p = i >> 16;
    int ra = (a < 255) ? a + 1 : 0;
    int rb = (b < 255) ? b + 1 : 0;
    o[i] = __half_as_ushort(__float2half(tables[(p << 16) + (ra << 8) + rb]));
}

// ===== pass A: unary search, full rows, 80 KB LDS -> 2 blocks/CU ============
__global__ __launch_bounds__(1024, 8) void ebm_unary(
    const float* __restrict__ x,
    float* __restrict__ ws) {

    __shared__ __align__(16) char smem[81920];
    float*  sE  = (float*)smem;               // 65536 B
    float4* sME = (float4*)(smem + 65536);    // 16384 B

    int tid = threadIdx.x;
    {
        const float4* w4 = (const float4*)ws;
        float4* dE = (float4*)sE;
#pragma unroll
        for (int k = 0; k < 4; ++k) dE[tid + 1024 * k] = w4[tid + 1024 * k];
        sME[tid] = w4[8192 + tid];
    }
    __syncthreads();

    const float*  CU = ws + 40960;
    const __half* Wg = (const __half*)(ws + 43008);
    int row = blockIdx.x * 1024 + tid;        // 256 blocks
    const float4* x4  = (const float4*)x + (size_t)row * 16;
    const float4* sE4 = (const float4*)sE;

    float acc = 0.f;
#pragma unroll
    for (int g = 0; g < 16; ++g) {
        float4 xg = x4[g];
        float xf[4] = {xg.x, xg.y, xg.z, xg.w};
        int t[4];
#pragma unroll
        for (int j = 0; j < 4; ++j) {
            const float* cu = CU + (4 * g + j) * 16;     // uniform -> s_load
            int tt = 0;
#pragma unroll
            for (int k = 0; k < 15; ++k) tt += (xf[j] >= cu[k]);
            t[j] = tt;
        }
        float4 mu[4];
#pragma unroll
        for (int j = 0; j < 4; ++j) mu[j] = sME[(4 * g + j) * 16 + t[j]];
        int lo[4];
        float4 fu[4];
#pragma unroll
        for (int j = 0; j < 4; ++j) {
            int m = (xf[j] >= mu[j].x) + (xf[j] >= mu[j].y) + (xf[j] >= mu[j].z);
            lo[j] = 4 * t[j] + m;
            fu[j] = sE4[(4 * g + j) * 64 + lo[j]];
        }
#pragma unroll
        for (int j = 0; j < 4; ++j) {
            int c = 4 * lo[j] + (xf[j] >= fu[j].x) + (xf[j] >= fu[j].y) +
                    (xf[j] >= fu[j].z) + (xf[j] >= fu[j].w);
            acc += __half2float(Wg[(4 * g + j) * 256 + c]);
        }
    }
    ws[51200 + row] = acc;                    // coalesced partial logit
}

// ===== pass B: pair search + park-in-reused-LDS + T16 gather + finalize =====
__global__ __launch_bounds__(1024, 8) void ebm_pairf(
    const float* __restrict__ x,
    const int*   __restrict__ pairs,
    const float* __restrict__ tables_f32,
    const float* __restrict__ bias,
    const float* __restrict__ ws,
    const __half* __restrict__ T16,
    int useT16,
    float* __restrict__ out) {

    __shared__ __align__(16) char smem[81920];
    float*  sPE = (float*)smem;
    float4* sMP = (float4*)(smem + 65536);

    int tid = threadIdx.x;
    {
        const float4* w4 = (const float4*)ws;
        float4* dP = (float4*)sPE;
#pragma unroll
        for (int k = 0; k < 4; ++k) dP[tid + 1024 * k] = w4[4096 + tid + 1024 * k];
        sMP[tid] = w4[9216 + tid];
    }
    unsigned long long mask = 0;
#pragma unroll 1
    for (int k = 0; k < 2 * NPAIRS; ++k) mask |= 1ull << pairs[k];
    __syncthreads();

    const float* CP = ws + 41984;
    int row = blockIdx.x * 1024 + tid;
    const float4* x4  = (const float4*)x + (size_t)row * 16;
    const float4* sP4 = (const float4*)sPE;

    unsigned pw[16];
#pragma unroll
    for (int g = 0; g < 16; ++g) {
        float4 xg = x4[g];
        float xf[4] = {xg.x, xg.y, xg.z, xg.w};
        unsigned pword = 0;
#pragma unroll
        for (int j = 0; j < 4; ++j) {
            int f = 4 * g + j;
            if ((mask >> f) & 1) {            // wave-uniform skip
                const float* cp = CP + f * 16;
                int tt = 0;
#pragma unroll
                for (int k = 0; k < 15; ++k) tt += (xf[j] >= cp[k]);
                float4 mp = sMP[f * 16 + tt];
                int m = (xf[j] >= mp.x) + (xf[j] >= mp.y) + (xf[j] >= mp.z);
                int l2 = 4 * tt + m;
                float4 fp = sP4[f * 64 + l2];
                int c2 = 4 * l2 + (xf[j] >= fp.x) + (xf[j] >= fp.y) +
                         (xf[j] >= fp.z) + (xf[j] >= fp.w);
                pword |= (unsigned)c2 << (8 * j);
            }
        }
        pw[g] = pword;
    }

    __syncthreads();                          // searches done; reuse LDS as park
    unsigned* park = (unsigned*)smem;         // 68 B/thread: stride-17 dwords, 2-way
#pragma unroll
    for (int k = 0; k < 16; ++k) park[tid * 17 + k] = pw[k];
    __syncthreads();

    const unsigned char* me = (const unsigned char*)smem + tid * 68;
    float acc = bias[0] + ws[51200 + row];
    if (useT16) {
#pragma unroll
        for (int p = 0; p < NPAIRS; ++p) {
            int a = pairs[2 * p], b = pairs[2 * p + 1];   // uniform
            int li = me[a], ri = me[b];                   // ds_read_u8
            acc += __half2float(T16[(p << 16) + (li << 8) + ri]);
        }
    } else {
#pragma unroll
        for (int p = 0; p < NPAIRS; ++p) {
            int a = pairs[2 * p], b = pairs[2 * p + 1];
            int li = me[a], ri = me[b];
            int lb = (li < 255) ? li + 1 : 0, rb = (ri < 255) ? ri + 1 : 0;
            acc += tables_f32[(p << 16) + (lb << 8) + rb];
        }
    }
    out[row] = 1.0f / (1.0f + __expf(-acc));
}

// ===== mono fallback (round-7, proven) ======================================
__device__ __forceinline__ unsigned pick16(const unsigned* pw, int s) {
    unsigned v01 = (s & 1) ? pw[1]  : pw[0];
    unsigned v23 = (s & 1) ? pw[3]  : pw[2];
    unsigned v45 = (s & 1) ? pw[5]  : pw[4];
    unsigned v67 = (s & 1) ? pw[7]  : pw[6];
    unsigned v89 = (s & 1) ? pw[9]  : pw[8];
    unsigned vab = (s & 1) ? pw[11] : pw[10];
    unsigned vcd = (s & 1) ? pw[13] : pw[12];
    unsigned vef = (s & 1) ? pw[15] : pw[14];
    unsigned w0 = (s & 2) ? v23 : v01;
    unsigned w1 = (s & 2) ? v67 : v45;
    unsigned w2 = (s & 2) ? vab : v89;
    unsigned w3 = (s & 2) ? vef : vcd;
    unsigned u0 = (s & 4) ? w1 : w0;
    unsigned u1 = (s & 4) ? w3 : w2;
    return (s & 8) ? u1 : u0;
}

__global__ __launch_bounds__(1024) void ebm_mono(
    const float* __restrict__ x,
    const int*   __restrict__ pairs,
    const float* __restrict__ tables_f32,
    const float* __restrict__ bias,
    const float* __restrict__ ws,
    const __half* __restrict__ T16,
    int useT16,
    float*       __restrict__ out) {

    __shared__ float  sE[16384];
    __shared__ float  sPE[16384];
    __shared__ float4 sME[1024];
    __shared__ float4 sMP[1024];

    int tid = threadIdx.x;
    {
        const float4* w4 = (const float4*)ws;
        float4* dE = (float4*)sE;
        float4* dP = (float4*)sPE;
        for (int i = tid; i < 4096; i += 1024) {
            dE[i] = w4[i];
            dP[i] = w4[4096 + i];
        }
        sME[tid] = w4[8192 + tid];
        sMP[tid] = w4[9216 + tid];
    }
    const float*  CU = ws + 40960;
    const float*  CP = ws + 41984;
    const __half* Wg = (const __half*)(ws + 43008);
    float bias0 = bias[0];
    __syncthreads();

    int row = blockIdx.x * 1024 + tid;
    const float4* x4 = (const float4*)x + (size_t)row * 16;
    const float4* sE4 = (const float4*)sE;
    const float4* sP4 = (const float4*)sPE;

    float acc = 0.f;
    unsigned pw[16];
#pragma unroll
    for (int g = 0; g < 16; ++g) {
        float4 xg = x4[g];
        float xf[4] = {xg.x, xg.y, xg.z, xg.w};
        int t[4], t2[4];
#pragma unroll
        for (int j = 0; j < 4; ++j) {
            const float* cu = CU + (4 * g + j) * 16;
            int tt = 0;
#pragma unroll
            for (int k = 0; k < 15; ++k) tt += (xf[j] >= cu[k]);
            t[j] = tt;
        }
#pragma unroll
        for (int j = 0; j < 4; ++j) {
            const float* cp = CP + (4 * g + j) * 16;
            int tt = 0;
#pragma unroll
            for (int k = 0; k < 15; ++k) tt += (xf[j] >= cp[k]);
            t2[j] = tt;
        }
        float4 mu[4], mp[4];
#pragma unroll
        for (int j = 0; j < 4; ++j) mu[j] = sME[(4 * g + j) * 16 + t[j]];
#pragma unroll
        for (int j = 0; j < 4; ++j) mp[j] = sMP[(4 * g + j) * 16 + t2[j]];
        int lo[4], lo2[4];
        float4 fu[4], fp[4];
#pragma unroll
        for (int j = 0; j < 4; ++j) {
            int m = (xf[j] >= mu[j].x) + (xf[j] >= mu[j].y) + (xf[j] >= mu[j].z);
            lo[j] = 4 * t[j] + m;
            fu[j] = sE4[(4 * g + j) * 64 + lo[j]];
        }
#pragma unroll
        for (int j = 0; j < 4; ++j) {
            int m = (xf[j] >= mp[j].x) + (xf[j] >= mp[j].y) + (xf[j] >= mp[j].z);
            lo2[j] = 4 * t2[j] + m;
            fp[j] = sP4[(4 * g + j) * 64 + lo2[j]];
        }
#pragma unroll
        for (int j = 0; j < 4; ++j) {
            int c = 4 * lo[j] + (xf[j] >= fu[j].x) + (xf[j] >= fu[j].y) +
                    (xf[j] >= fu[j].z) + (xf[j] >= fu[j].w);
            acc += __half2float(Wg[(4 * g + j) * 256 + c]);
        }
        unsigned pword = 0;
#pragma unroll
        for (int j = 0; j < 4; ++j) {
            int c2 = 4 * lo2[j] + (xf[j] >= fp[j].x) + (xf[j] >= fp[j].y) +
                     (xf[j] >= fp[j].z) + (xf[j] >= fp[j].w);
            pword |= (unsigned)c2 << (8 * j);
        }
        pw[g] = pword;
    }

    if (useT16) {
#pragma unroll
        for (int p = 0; p < NPAIRS; ++p) {
            int a = pairs[2 * p], b = pairs[2 * p + 1];
            unsigned wa = pick16(pw, a >> 2);
            unsigned wb = pick16(pw, b >> 2);
            int li = (wa >> ((a & 3) * 8)) & 255;
            int ri = (wb >> ((b & 3) * 8)) & 255;
            acc += __half2float(T16[(p << 16) + (li << 8) + ri]);
        }
    } else {
#pragma unroll
        for (int p = 0; p < NPAIRS; ++p) {
            int a = pairs[2 * p], b = pairs[2 * p + 1];
            unsigned wa = pick16(pw, a >> 2);
            unsigned wb = pick16(pw, b >> 2);
            int li = (wa >> ((a & 3) * 8)) & 255;
            int ri = (wb >> ((b & 3) * 8)) & 255;
            int lb = (li < 255) ? li + 1 : 0;
            int rb = (ri < 255) ? ri + 1 : 0;
            acc += tables_f32[(p << 16) + (lb << 8) + rb];
        }
    }
    out[row] = 1.0f / (1.0f + __expf(-(acc + bias0)));
}

extern "C" void kernel_launch(void* const* d_in, const int* in_sizes, int n_in,
                              void* d_out, int out_size, void* d_ws, size_t ws_size,
                              hipStream_t stream) {
    const float* x          = (const float*)d_in[0];
    const float* edges      = (const float*)d_in[1];
    const float* w          = (const float*)d_in[2];
    const float* pair_edges = (const float*)d_in[3];
    const int*   pairs      = (const int*)d_in[4];
    const float* tables     = (const float*)d_in[5];
    const float* bias       = (const float*)d_in[6];
    float* out = (float*)d_out;
    float* ws  = (float*)d_ws;

    if (ws_size >= (size_t)5447680) {
        // split path: prep_all -> unary -> pairf
        __half* T16 = (__half*)((char*)d_ws + 1253376);
        ebm_prep_all<<<2048, 1024, 0, stream>>>(edges, pair_edges, w, tables,
                                                ws, (unsigned short*)T16);
        ebm_unary<<<256, 1024, 0, stream>>>(x, ws);
        ebm_pairf<<<256, 1024, 0, stream>>>(x, pairs, tables, bias, ws, T16, 1, out);
    } else {
        // mono fallback (round-7 structure)
        int useT16 = (ws_size >= (size_t)4399104) ? 1 : 0;
        __half* T16 = (__half*)((char*)d_ws + 204800);
        ebm_prep<<<64, 256, 0, stream>>>(edges, pair_edges, w, ws);
        if (useT16) {
            ebm_prep_tables<<<2048, 1024, 0, stream>>>(tables, (unsigned short*)T16);
        }
        ebm_mono<<<256, 1024, 0, stream>>>(x, pairs, tables, bias, ws, T16, useT16, out);
    }
}

// Round 10
// 213.786 us; speedup vs baseline: 1.0208x; 1.0208x over previous
//
#include <hip/hip_runtime.h>
#include <hip/hip_fp16.h>

#define NBINS 255
#define NPAIRS 32
#define BIGF 3.0e38f

// ws float-index layout (split path):
//  [0     ,16384 ) E   [64][256] fp32, tail BIGF
//  [16384 ,32768 ) PE
//  [32768 ,36864 ) ME  [64][64] mids e[4m+3] (pad BIGF)
//  [36864 ,40960 ) MP
//  [40960 ,41984 ) CU  [64][16] coarse e[16j+15] (pad BIGF)
//  [41984 ,43008 ) CP
//  [43008 ,51200 ) W16 [64][256] fp16 PRE-SHIFTED
//  [51200 ,313344) P   [262144] fp32 unary partial logits
//  [313344,575488) G   [262144] fp32 pair partial sums
//  byte 2301952.. T16 [32][256][256] fp16 PRE-SHIFTED  (split: ws>=6496256)
//  byte 204800 .. T16 (mono fallback: ws>=4399104)

__device__ __forceinline__ void prep_edge_elem(int i,
        const float* __restrict__ edges, const float* __restrict__ pair_edges,
        const float* __restrict__ w, float* __restrict__ ws) {
    int f = i >> 8, j = i & 255;
    float* E  = ws;
    float* PE = ws + 16384;
    float* ME = ws + 32768;
    float* MP = ws + 36864;
    float* CU = ws + 40960;
    float* CP = ws + 41984;
    __half* W = (__half*)(ws + 43008);
    E[i]  = (j < NBINS) ? edges[f * NBINS + j]      : BIGF;
    PE[i] = (j < NBINS) ? pair_edges[f * NBINS + j] : BIGF;
    int src = (j < 255) ? j + 1 : 0;
    W[i]  = __float2half(w[f * 256 + src]);
    if (j < 64) {
        int idx = 4 * j + 3;
        ME[f * 64 + j] = (idx < NBINS) ? edges[f * NBINS + idx]      : BIGF;
        MP[f * 64 + j] = (idx < NBINS) ? pair_edges[f * NBINS + idx] : BIGF;
    }
    if (j < 16) {
        CU[f * 16 + j] = (j < 15) ? edges[f * NBINS + 16 * j + 15]      : BIGF;
        CP[f * 16 + j] = (j < 15) ? pair_edges[f * NBINS + 16 * j + 15] : BIGF;
    }
}

__global__ void ebm_prep_all(const float* __restrict__ edges,
                             const float* __restrict__ pair_edges,
                             const float* __restrict__ w,
                             const float* __restrict__ tables,
                             float* __restrict__ ws,
                             unsigned short* __restrict__ T16o) {
    int i = blockIdx.x * blockDim.x + threadIdx.x;   // 2097152 threads
    int b = i & 255, a = (i >> 8) & 255, p = i >> 16;
    int ra = (a < 255) ? a + 1 : 0;
    int rb = (b < 255) ? b + 1 : 0;
    T16o[i] = __half_as_ushort(__float2half(tables[(p << 16) + (ra << 8) + rb]));
    if (i < 16384) prep_edge_elem(i, edges, pair_edges, w, ws);
}

__global__ void ebm_prep(const float* __restrict__ edges,
                         const float* __restrict__ pair_edges,
                         const float* __restrict__ w,
                         float* __restrict__ ws) {
    int i = blockIdx.x * blockDim.x + threadIdx.x;   // 16384 threads
    prep_edge_elem(i, edges, pair_edges, w, ws);
}

__global__ void ebm_prep_tables(const float* __restrict__ tables,
                                unsigned short* __restrict__ o) {
    int i = blockIdx.x * blockDim.x + threadIdx.x;
    int b = i & 255, a = (i >> 8) & 255, p = i >> 16;
    int ra = (a < 255) ? a + 1 : 0;
    int rb = (b < 255) ? b + 1 : 0;
    o[i] = __half_as_ushort(__float2half(tables[(p << 16) + (ra << 8) + rb]));
}

// ===== heterogeneous worker: even-groups = unary, odd-groups = pair =========
// 512 blocks x 1024 threads, 80 KB LDS -> 2 blocks/CU (one of each kind).
// XCD pairing: branch=(blk>>3)&1, half=(blk>>4)*8+(blk&7) -> the unary and
// pair blocks for the same 1024 rows land on the same XCD (round-robin blk%8).
__global__ __launch_bounds__(1024, 8) void ebm_work(
    const float* __restrict__ x,
    const int*   __restrict__ pairs,
    const __half* __restrict__ T16,
    float* __restrict__ ws) {

    __shared__ __align__(16) char smem[81920];

    int tid = threadIdx.x;
    int blk = blockIdx.x;
    int branch = (blk >> 3) & 1;
    int half   = ((blk >> 4) << 3) | (blk & 7);      // [0,256)
    int row    = half * 1024 + tid;
    const float4* x4 = (const float4*)x + (size_t)row * 16;
    const float4* w4 = (const float4*)ws;

    if (branch == 0) {
        // ---------------- unary branch ----------------
        float*  sE  = (float*)smem;                  // 64 KB
        float4* sME = (float4*)(smem + 65536);       // 16 KB
        {
            float4* dE = (float4*)sE;
#pragma unroll
            for (int k = 0; k < 4; ++k) dE[tid + 1024 * k] = w4[tid + 1024 * k];
            sME[tid] = w4[8192 + tid];
        }
        __syncthreads();

        const float*  CUc = ws + 40960;
        const __half* Wg  = (const __half*)(ws + 43008);
        const float4* sE4 = (const float4*)sE;

        float acc = 0.f;
        float4 xg = x4[0];
#pragma unroll
        for (int g = 0; g < 16; ++g) {
            float4 xnext = xg;
            if (g < 15) xnext = x4[g + 1];
            float xf[4] = {xg.x, xg.y, xg.z, xg.w};
            int t[4];
#pragma unroll
            for (int j = 0; j < 4; ++j) {
                const float* cu = CUc + (4 * g + j) * 16;    // uniform -> s_load
                int tt = 0;
#pragma unroll
                for (int k = 0; k < 15; ++k) tt += (xf[j] >= cu[k]);
                t[j] = tt;
            }
            float4 mu[4];
#pragma unroll
            for (int j = 0; j < 4; ++j) mu[j] = sME[(4 * g + j) * 16 + t[j]];
            int lo[4];
            float4 fu[4];
#pragma unroll
            for (int j = 0; j < 4; ++j) {
                int m = (xf[j] >= mu[j].x) + (xf[j] >= mu[j].y) + (xf[j] >= mu[j].z);
                lo[j] = 4 * t[j] + m;
                fu[j] = sE4[(4 * g + j) * 64 + lo[j]];
            }
#pragma unroll
            for (int j = 0; j < 4; ++j) {
                int c = 4 * lo[j] + (xf[j] >= fu[j].x) + (xf[j] >= fu[j].y) +
                        (xf[j] >= fu[j].z) + (xf[j] >= fu[j].w);
                acc += __half2float(Wg[(4 * g + j) * 256 + c]);
            }
            xg = xnext;
        }
        ws[51200 + row] = acc;
    } else {
        // ---------------- pair branch ----------------
        float*  sPE = (float*)smem;
        float4* sMP = (float4*)(smem + 65536);
        {
            float4* dP = (float4*)sPE;
#pragma unroll
            for (int k = 0; k < 4; ++k) dP[tid + 1024 * k] = w4[4096 + tid + 1024 * k];
            sMP[tid] = w4[9216 + tid];
        }
        unsigned long long mask = 0;
#pragma unroll 1
        for (int k = 0; k < 2 * NPAIRS; ++k) mask |= 1ull << pairs[k];
        __syncthreads();

        const float* CPc = ws + 41984;
        const float4* sP4 = (const float4*)sPE;

        unsigned pw[16];
        float4 xg = x4[0];
#pragma unroll
        for (int g = 0; g < 16; ++g) {
            float4 xnext = xg;
            if (g < 15) xnext = x4[g + 1];
            float xf[4] = {xg.x, xg.y, xg.z, xg.w};
            unsigned pword = 0;
#pragma unroll
            for (int j = 0; j < 4; ++j) {
                int f = 4 * g + j;
                if ((mask >> f) & 1) {                  // wave-uniform skip
                    const float* cp = CPc + f * 16;
                    int tt = 0;
#pragma unroll
                    for (int k = 0; k < 15; ++k) tt += (xf[j] >= cp[k]);
                    float4 mp = sMP[f * 16 + tt];
                    int m = (xf[j] >= mp.x) + (xf[j] >= mp.y) + (xf[j] >= mp.z);
                    int l2 = 4 * tt + m;
                    float4 fp = sP4[f * 64 + l2];
                    int c2 = 4 * l2 + (xf[j] >= fp.x) + (xf[j] >= fp.y) +
                             (xf[j] >= fp.z) + (xf[j] >= fp.w);
                    pword |= (unsigned)c2 << (8 * j);
                }
            }
            pw[g] = pword;
            xg = xnext;
        }

        __syncthreads();                   // searches done; reuse LDS as park
        unsigned* park = (unsigned*)smem;  // 68 B/thread (stride-17 dwords, 2-way)
#pragma unroll
        for (int k = 0; k < 16; ++k) park[tid * 17 + k] = pw[k];
        __syncthreads();

        const unsigned char* me = (const unsigned char*)smem + tid * 68;
        float acc = 0.f;
#pragma unroll
        for (int p = 0; p < NPAIRS; ++p) {
            int a = pairs[2 * p], b = pairs[2 * p + 1];   // uniform
            int li = me[a], ri = me[b];                   // ds_read_u8
            acc += __half2float(T16[(p << 16) + (li << 8) + ri]);
        }
        ws[313344 + row] = acc;
    }
}

__global__ __launch_bounds__(1024) void ebm_final(
    const float* __restrict__ ws,
    const float* __restrict__ bias,
    float* __restrict__ out) {
    int i = blockIdx.x * 1024 + threadIdx.x;
    float z = ws[51200 + i] + ws[313344 + i] + bias[0];
    out[i] = 1.0f / (1.0f + __expf(-z));
}

// ===== mono fallback (round-7, proven) ======================================
__device__ __forceinline__ unsigned pick16(const unsigned* pw, int s) {
    unsigned v01 = (s & 1) ? pw[1]  : pw[0];
    unsigned v23 = (s & 1) ? pw[3]  : pw[2];
    unsigned v45 = (s & 1) ? pw[5]  : pw[4];
    unsigned v67 = (s & 1) ? pw[7]  : pw[6];
    unsigned v89 = (s & 1) ? pw[9]  : pw[8];
    unsigned vab = (s & 1) ? pw[11] : pw[10];
    unsigned vcd = (s & 1) ? pw[13] : pw[12];
    unsigned vef = (s & 1) ? pw[15] : pw[14];
    unsigned w0 = (s & 2) ? v23 : v01;
    unsigned w1 = (s & 2) ? v67 : v45;
    unsigned w2 = (s & 2) ? vab : v89;
    unsigned w3 = (s & 2) ? vef : vcd;
    unsigned u0 = (s & 4) ? w1 : w0;
    unsigned u1 = (s & 4) ? w3 : w2;
    return (s & 8) ? u1 : u0;
}

__global__ __launch_bounds__(1024) void ebm_mono(
    const float* __restrict__ x,
    const int*   __restrict__ pairs,
    const float* __restrict__ tables_f32,
    const float* __restrict__ bias,
    const float* __restrict__ ws,
    const __half* __restrict__ T16,
    int useT16,
    float*       __restrict__ out) {

    __shared__ float  sE[16384];
    __shared__ float  sPE[16384];
    __shared__ float4 sME[1024];
    __shared__ float4 sMP[1024];

    int tid = threadIdx.x;
    {
        const float4* w4 = (const float4*)ws;
        float4* dE = (float4*)sE;
        float4* dP = (float4*)sPE;
        for (int i = tid; i < 4096; i += 1024) {
            dE[i] = w4[i];
            dP[i] = w4[4096 + i];
        }
        sME[tid] = w4[8192 + tid];
        sMP[tid] = w4[9216 + tid];
    }
    const float*  CU = ws + 40960;
    const float*  CP = ws + 41984;
    const __half* Wg = (const __half*)(ws + 43008);
    float bias0 = bias[0];
    __syncthreads();

    int row = blockIdx.x * 1024 + tid;
    const float4* x4 = (const float4*)x + (size_t)row * 16;
    const float4* sE4 = (const float4*)sE;
    const float4* sP4 = (const float4*)sPE;

    float acc = 0.f;
    unsigned pw[16];
#pragma unroll
    for (int g = 0; g < 16; ++g) {
        float4 xg = x4[g];
        float xf[4] = {xg.x, xg.y, xg.z, xg.w};
        int t[4], t2[4];
#pragma unroll
        for (int j = 0; j < 4; ++j) {
            const float* cu = CU + (4 * g + j) * 16;
            int tt = 0;
#pragma unroll
            for (int k = 0; k < 15; ++k) tt += (xf[j] >= cu[k]);
            t[j] = tt;
        }
#pragma unroll
        for (int j = 0; j < 4; ++j) {
            const float* cp = CP + (4 * g + j) * 16;
            int tt = 0;
#pragma unroll
            for (int k = 0; k < 15; ++k) tt += (xf[j] >= cp[k]);
            t2[j] = tt;
        }
        float4 mu[4], mp[4];
#pragma unroll
        for (int j = 0; j < 4; ++j) mu[j] = sME[(4 * g + j) * 16 + t[j]];
#pragma unroll
        for (int j = 0; j < 4; ++j) mp[j] = sMP[(4 * g + j) * 16 + t2[j]];
        int lo[4], lo2[4];
        float4 fu[4], fp[4];
#pragma unroll
        for (int j = 0; j < 4; ++j) {
            int m = (xf[j] >= mu[j].x) + (xf[j] >= mu[j].y) + (xf[j] >= mu[j].z);
            lo[j] = 4 * t[j] + m;
            fu[j] = sE4[(4 * g + j) * 64 + lo[j]];
        }
#pragma unroll
        for (int j = 0; j < 4; ++j) {
            int m = (xf[j] >= mp[j].x) + (xf[j] >= mp[j].y) + (xf[j] >= mp[j].z);
            lo2[j] = 4 * t2[j] + m;
            fp[j] = sP4[(4 * g + j) * 64 + lo2[j]];
        }
#pragma unroll
        for (int j = 0; j < 4; ++j) {
            int c = 4 * lo[j] + (xf[j] >= fu[j].x) + (xf[j] >= fu[j].y) +
                    (xf[j] >= fu[j].z) + (xf[j] >= fu[j].w);
            acc += __half2float(Wg[(4 * g + j) * 256 + c]);
        }
        unsigned pword = 0;
#pragma unroll
        for (int j = 0; j < 4; ++j) {
            int c2 = 4 * lo2[j] + (xf[j] >= fp[j].x) + (xf[j] >= fp[j].y) +
                     (xf[j] >= fp[j].z) + (xf[j] >= fp[j].w);
            pword |= (unsigned)c2 << (8 * j);
        }
        pw[g] = pword;
    }

    if (useT16) {
#pragma unroll
        for (int p = 0; p < NPAIRS; ++p) {
            int a = pairs[2 * p], b = pairs[2 * p + 1];
            unsigned wa = pick16(pw, a >> 2);
            unsigned wb = pick16(pw, b >> 2);
            int li = (wa >> ((a & 3) * 8)) & 255;
            int ri = (wb >> ((b & 3) * 8)) & 255;
            acc += __half2float(T16[(p << 16) + (li << 8) + ri]);
        }
    } else {
#pragma unroll
        for (int p = 0; p < NPAIRS; ++p) {
            int a = pairs[2 * p], b = pairs[2 * p + 1];
            unsigned wa = pick16(pw, a >> 2);
            unsigned wb = pick16(pw, b >> 2);
            int li = (wa >> ((a & 3) * 8)) & 255;
            int ri = (wb >> ((b & 3) * 8)) & 255;
            int lb = (li < 255) ? li + 1 : 0;
            int rb = (ri < 255) ? ri + 1 : 0;
            acc += tables_f32[(p << 16) + (lb << 8) + rb];
        }
    }
    out[row] = 1.0f / (1.0f + __expf(-(acc + bias0)));
}

extern "C" void kernel_launch(void* const* d_in, const int* in_sizes, int n_in,
                              void* d_out, int out_size, void* d_ws, size_t ws_size,
                              hipStream_t stream) {
    const float* x          = (const float*)d_in[0];
    const float* edges      = (const float*)d_in[1];
    const float* w          = (const float*)d_in[2];
    const float* pair_edges = (const float*)d_in[3];
    const int*   pairs      = (const int*)d_in[4];
    const float* tables     = (const float*)d_in[5];
    const float* bias       = (const float*)d_in[6];
    float* out = (float*)d_out;
    float* ws  = (float*)d_ws;

    if (ws_size >= (size_t)6496256) {
        __half* T16 = (__half*)((char*)d_ws + 2301952);
        ebm_prep_all<<<2048, 1024, 0, stream>>>(edges, pair_edges, w, tables,
                                                ws, (unsigned short*)T16);
        ebm_work<<<512, 1024, 0, stream>>>(x, pairs, T16, ws);
        ebm_final<<<256, 1024, 0, stream>>>(ws, bias, out);
    } else {
        int useT16 = (ws_size >= (size_t)4399104) ? 1 : 0;
        __half* T16 = (__half*)((char*)d_ws + 204800);
        ebm_prep<<<64, 256, 0, stream>>>(edges, pair_edges, w, ws);
        if (useT16) {
            ebm_prep_tables<<<2048, 1024, 0, stream>>>(tables, (unsigned short*)T16);
        }
        ebm_mono<<<256, 1024, 0, stream>>>(x, pairs, tables, bias, ws, T16, useT16, out);
    }
}